// Round 1
// baseline (238.516 us; speedup 1.0000x reference)
//
#include <hip/hip_runtime.h>
#include <hip/hip_bf16.h>

#define NQ 6

typedef __attribute__((ext_vector_type(8))) short short8;
typedef __attribute__((ext_vector_type(4))) float floatx4;

// ---------------- ws layout (bytes) ----------------
// U_circ : float2[64*64]        @ 0        (32768 B)
// Mq     : float[18]            @ 32768
// cq     : float[3]             @ 32840
// W1bf   : short[64*2048]       @ 36864    (262144 B)
// qpart  : float[B*3]           @ 301056
#define WS_MQ_F   8192        // float offset of Mq
#define WS_CQ_F   (8192+18)
#define WS_W1BF_B 36864
#define WS_QPART_B 301056

// ============ K0: prep — U_circ columns, Mq/cq, W1->bf16 ============
__global__ __launch_bounds__(64) void prep_kernel(
    const float* __restrict__ qw, int n_layers,
    const float* __restrict__ W1, const float* __restrict__ Wq,
    const float* __restrict__ bq, const float* __restrict__ Wf,
    const float* __restrict__ bf, float* __restrict__ ws_f,
    short* __restrict__ w1bf)
{
    const int blk  = blockIdx.x;
    const int lane = threadIdx.x;

    if (blk == 0) {
        // Mq[j][w] = sum_m Wf[j][64+m] * Wq[m][w];  cq[j] = sum_m Wf[j][64+m]*bq[m] + bf[j]
        if (lane < 18) {
            int j = lane / 6, wi = lane % 6;
            float s = 0.f;
            for (int m = 0; m < 16; ++m) s += Wf[j*80 + 64 + m] * Wq[m*6 + wi];
            ws_f[WS_MQ_F + lane] = s;
        } else if (lane < 21) {
            int j = lane - 18;
            float s = bf[j];
            for (int m = 0; m < 16; ++m) s += Wf[j*80 + 64 + m] * bq[m];
            ws_f[WS_CQ_F + j] = s;
        }
    } else if (blk <= 64) {
        // U_circ column j: amplitudes-in-lanes, one wave
        const int j = blk - 1;
        float re = (lane == j) ? 1.f : 0.f;
        float im = 0.f;
        for (int l = 0; l < n_layers; ++l) {
            for (int w = 0; w < NQ; ++w) {
                const float* g = qw + (l*NQ + w)*3;
                float phi = g[0], th = g[1], om = g[2];
                float c, s;  __sincosf(0.5f*th, &s, &c);
                float sa, ca; __sincosf(0.5f*(phi+om), &sa, &ca);
                float sb, cb; __sincosf(0.5f*(phi-om), &sb, &cb);
                // U00=c(ca-i sa)  U01=-s(cb+i sb)  U10=s(cb-i sb)  U11=c(ca+i sa)
                float u00r =  c*ca, u00i = -c*sa;
                float u01r = -s*cb, u01i = -s*sb;
                float u10r =  s*cb, u10i = -s*sb;
                float u11r =  c*ca, u11i =  c*sa;
                int p = 5 - w, mask = 1 << p;
                float pre = __shfl_xor(re, mask, 64);
                float pim = __shfl_xor(im, mask, 64);
                int b = (lane >> p) & 1;
                float mr = b ? u11r : u00r, mi = b ? u11i : u00i;
                float pr = b ? u10r : u01r, pi = b ? u10i : u01i;
                float nre = mr*re - mi*im + pr*pre - pi*pim;
                float nim = mr*im + mi*re + pr*pim + pi*pre;
                re = nre; im = nim;
            }
            int r = l % (NQ-1) + 1;
            for (int w = 0; w < NQ; ++w) {
                int tgt = (w + r) % NQ;
                int tmask = 1 << (5 - tgt);
                float pre = __shfl_xor(re, tmask, 64);
                float pim = __shfl_xor(im, tmask, 64);
                int cs = (lane >> (5 - w)) & 1;
                re = cs ? pre : re;
                im = cs ? pim : im;
            }
        }
        ws_f[(lane*64 + j)*2 + 0] = re;   // U[i=lane][j].re
        ws_f[(lane*64 + j)*2 + 1] = im;
    } else {
        // W1 fp32 -> bf16 (same [n][k] row-major layout), blocks 65..320
        int idx = (blk - 65)*512 + lane*8;
        if (idx < 64*2048) {
            float4 a0 = *(const float4*)(W1 + idx);
            float4 a1 = *(const float4*)(W1 + idx + 4);
            union { short8 v; __hip_bfloat162 h[4]; } u;
            float2 f;
            f.x=a0.x; f.y=a0.y; u.h[0] = __float22bfloat162_rn(f);
            f.x=a0.z; f.y=a0.w; u.h[1] = __float22bfloat162_rn(f);
            f.x=a1.x; f.y=a1.y; u.h[2] = __float22bfloat162_rn(f);
            f.x=a1.z; f.y=a1.w; u.h[3] = __float22bfloat162_rn(f);
            *(short8*)(w1bf + idx) = u.v;
        }
    }
}

// ============ K1: qpart[b][0..2] = Mq @ z(b) + cq ============
__global__ __launch_bounds__(256) void qpart_kernel(
    const float* __restrict__ xq, const float2* __restrict__ U,
    const float* __restrict__ ws_f, float* __restrict__ qpart, int B)
{
    const int lane = threadIdx.x & 63;
    const int t = __builtin_amdgcn_readfirstlane((int)(threadIdx.x >> 6)); // wave id: i-chunk
    const int b = blockIdx.x*64 + lane;

    // product state a[64]: bit for qubit q at position (5-q)
    float a[64];
    const float* x = xq + (size_t)b*6;
    a[0] = 1.f;
    #pragma unroll
    for (int q = 0; q < 6; ++q) {
        float c, s; __sincosf(0.5f*x[q], &s, &c);
        const int sz = 1 << q;
        #pragma unroll
        for (int m = sz-1; m >= 0; --m) {
            float v = a[m];
            a[2*m+1] = v*s;
            a[2*m+0] = v*c;
        }
    }

    float zp[6] = {0,0,0,0,0,0};
    const float2* Urow = U + t*16*64;
    for (int ii = 0; ii < 16; ++ii) {
        float rr = 0.f, ri = 0.f;
        #pragma unroll
        for (int j = 0; j < 64; ++j) {
            float2 u = Urow[ii*64 + j];   // wave-uniform -> scalar loads
            rr += u.x * a[j];
            ri += u.y * a[j];
        }
        float p = rr*rr + ri*ri;
        int i = t*16 + ii;
        #pragma unroll
        for (int w = 0; w < 6; ++w) zp[w] += ((i >> (5-w)) & 1) ? -p : p;
    }

    __shared__ float zbuf[4][64][6];
    #pragma unroll
    for (int w = 0; w < 6; ++w) zbuf[t][lane][w] = zp[w];
    __syncthreads();
    if (t == 0) {
        float z[6];
        #pragma unroll
        for (int w = 0; w < 6; ++w)
            z[w] = zbuf[0][lane][w] + zbuf[1][lane][w] + zbuf[2][lane][w] + zbuf[3][lane][w];
        #pragma unroll
        for (int j = 0; j < 3; ++j) {
            float v = ws_f[WS_CQ_F + j];
            #pragma unroll
            for (int w = 0; w < 6; ++w) v += ws_f[WS_MQ_F + j*6 + w] * z[w];
            qpart[(size_t)b*3 + j] = v;
        }
    }
}

// ============ K2: fused GEMM + ReLU + 3-wide head + qpart ============
__global__ __launch_bounds__(128) void gemm_kernel(
    const float* __restrict__ xc, const short* __restrict__ w1bf,
    const float* __restrict__ b1, const float* __restrict__ Wf,
    const float* __restrict__ qpart, float* __restrict__ out, int B)
{
    const int tid = threadIdx.x;
    const int wv  = tid >> 6;          // 0..1
    const int l   = tid & 63;
    const int blk = blockIdx.x;

    const int row  = blk*32 + wv*16 + (l & 15);   // A fragment: m = lane&15
    const int koff = (l >> 4) * 8;                // k = (lane>>4)*8 + j

    const float* ap = xc + (size_t)row*2048 + koff;
    const short* bp = w1bf + (l & 15)*2048 + koff;

    floatx4 acc0 = {0,0,0,0}, acc1 = {0,0,0,0}, acc2 = {0,0,0,0}, acc3 = {0,0,0,0};

    #pragma unroll 4
    for (int kk = 0; kk < 64; ++kk) {
        float4 a0 = *(const float4*)ap;
        float4 a1 = *(const float4*)(ap + 4);
        union { short8 v; __hip_bfloat162 h[4]; } af;
        float2 f;
        f.x=a0.x; f.y=a0.y; af.h[0] = __float22bfloat162_rn(f);
        f.x=a0.z; f.y=a0.w; af.h[1] = __float22bfloat162_rn(f);
        f.x=a1.x; f.y=a1.y; af.h[2] = __float22bfloat162_rn(f);
        f.x=a1.z; f.y=a1.w; af.h[3] = __float22bfloat162_rn(f);

        short8 b0 = *(const short8*)(bp);
        short8 bv1 = *(const short8*)(bp + 16*2048);
        short8 b2 = *(const short8*)(bp + 32*2048);
        short8 b3 = *(const short8*)(bp + 48*2048);

        acc0 = __builtin_amdgcn_mfma_f32_16x16x32_bf16(af.v, b0,  acc0, 0, 0, 0);
        acc1 = __builtin_amdgcn_mfma_f32_16x16x32_bf16(af.v, bv1, acc1, 0, 0, 0);
        acc2 = __builtin_amdgcn_mfma_f32_16x16x32_bf16(af.v, b2,  acc2, 0, 0, 0);
        acc3 = __builtin_amdgcn_mfma_f32_16x16x32_bf16(af.v, b3,  acc3, 0, 0, 0);

        ap += 32;
        bp += 32;
    }

    // epilogue: C layout col=lane&15(+16t), row=(lane>>4)*4+r
    __shared__ float cl[32][65];
    const int rbase = wv*16 + (l >> 4)*4;
    const int c0 = l & 15;
    float bb0 = b1[c0], bb1 = b1[16 + c0], bb2 = b1[32 + c0], bb3 = b1[48 + c0];
    #pragma unroll
    for (int r = 0; r < 4; ++r) {
        cl[rbase + r][ 0 + c0] = fmaxf(acc0[r] + bb0, 0.f);
        cl[rbase + r][16 + c0] = fmaxf(acc1[r] + bb1, 0.f);
        cl[rbase + r][32 + c0] = fmaxf(acc2[r] + bb2, 0.f);
        cl[rbase + r][48 + c0] = fmaxf(acc3[r] + bb3, 0.f);
    }
    __syncthreads();

    const int rr = tid & 31;
    const int j  = tid >> 5;    // 0..3, use 0..2
    if (j < 3) {
        float v = 0.f;
        #pragma unroll
        for (int col = 0; col < 64; ++col) v += Wf[j*80 + col] * cl[rr][col];
        int g = blk*32 + rr;
        out[(size_t)g*3 + j] = v + qpart[(size_t)g*3 + j];
    }
}

extern "C" void kernel_launch(void* const* d_in, const int* in_sizes, int n_in,
                              void* d_out, int out_size, void* d_ws, size_t ws_size,
                              hipStream_t stream) {
    const float* xc = (const float*)d_in[0];
    const float* xq = (const float*)d_in[1];
    const float* W1 = (const float*)d_in[2];
    const float* b1 = (const float*)d_in[3];
    const float* qw = (const float*)d_in[4];
    const float* Wq = (const float*)d_in[5];
    const float* bq = (const float*)d_in[6];
    const float* Wf = (const float*)d_in[7];
    const float* bf = (const float*)d_in[8];
    float* out = (float*)d_out;

    const int B = in_sizes[1] / NQ;                 // 16384
    const int n_layers = in_sizes[4] / (NQ * 3);    // 3

    char* ws = (char*)d_ws;
    float*  ws_f  = (float*)ws;
    float2* U     = (float2*)ws;
    short*  w1bf  = (short*)(ws + WS_W1BF_B);
    float*  qpart = (float*)(ws + WS_QPART_B);

    prep_kernel<<<dim3(321), dim3(64), 0, stream>>>(qw, n_layers, W1, Wq, bq, Wf, bf, ws_f, w1bf);
    qpart_kernel<<<dim3(B/64), dim3(256), 0, stream>>>(xq, U, ws_f, qpart, B);
    gemm_kernel<<<dim3(B/32), dim3(128), 0, stream>>>(xc, w1bf, b1, Wf, qpart, out, B);
}